// Round 21
// baseline (122.562 us; speedup 1.0000x reference)
//
#include <hip/hip_runtime.h>
#include <hip/hip_cooperative_groups.h>
#include <stdint.h>

namespace cg = cooperative_groups;

typedef unsigned int uint;
typedef unsigned long long ull;

// B=2, N=5120, F=10240, H=W=256. Bit-exact fp32 replication of the reference
// (contract off, IEEE div). Pipeline (3 dispatches):
//   k_prep (COOPERATIVE, 80 blk x 256): phase0 zero cnt + init packed |sync|
//     phase1 transform-fused face records + zmin bucket counts |sync|
//     phase2 prefix scan (blocks 0..B-1, 256 thr x 16 buckets) |sync|
//     phase3 scatter to z-sorted records + bbox + per-64-chunk lb array.
//   k_raster: WAVE-AUTONOMOUS (unchanged from R20/R18): one wave = 8x8-px
//     tile x z-segment, 1 px/lane, no LDS/barriers; per 64-face chunk:
//     bbox+SAT cull, ballot, readlane-broadcast survivors, branchless test,
//     best = packed u64 (z_bits<<32|orig_f); poll+publish per GROUP chunks;
//     exit when __all(lb >= known + TOL) [NaN-safe].
//   k_sample: winner barycentrics recomputed bit-identically + bilinear.
// Winner = lexicographic (z, orig_f) min == reference chunked argmin.
// Sorted record s3 = 3 float4/face: {v0x,v0y,e1x,e1y} {e2x,e2y,inv,z0}
//                                   {z1,z2,bits(orig_f),lb}; bbox separate.

#define K_BUCKETS 4096
#define ZLO 0.0f
#define ZHI 20.0f
#define TOL 2.5e-4f      // >=50x the ~5e-6 fp slack (z is a convex comb.)
#define NSEG 64          // z-segmentation granularity (cps = ceil(160/64) = 3)
#define PAD 0.004f       // conservative cull pad (>=100x fp slack)
#define GROUP 4          // chunks (of 64 faces) between poll/publish

__device__ __forceinline__ float clip11(float t) {
  return fminf(1.0f, fmaxf(-1.0f, t));
}

__device__ __forceinline__ float RL(float v, int j) {
  return __uint_as_float((uint)__builtin_amdgcn_readlane((int)__float_as_uint(v), j));
}

// cooperative prep: zero/init -> face records+counts -> prefix -> scatter
__global__ void __launch_bounds__(256) k_prep(const int* __restrict__ faces,
                                              const float* __restrict__ hv,
                                              const float* __restrict__ cam,
                                              const float* __restrict__ camn,
                                              float4* __restrict__ fh4,
                                              float4* __restrict__ fa4,
                                              uint* __restrict__ bkt,
                                              uint* __restrict__ cnt,
                                              uint* __restrict__ off,
                                              float4* __restrict__ s3,
                                              float4* __restrict__ bboxs,
                                              float* __restrict__ lbC,
                                              ull* __restrict__ packed,
                                              int np, int F, int N, int B,
                                              int NCH64) {
#pragma clang fp contract(off)
  cg::grid_group grid = cg::this_grid();
  int t = blockIdx.x * 256 + threadIdx.x;
  int nthr = gridDim.x * 256;
  int BF = B * F;
  int ncnt = B * K_BUCKETS;

  // ---- phase 0: zero bucket counts, init packed z-buffer ----
  for (int i = t; i < np; i += nthr) packed[i] = 0xFFFFFFFFFFFFFFFFull;
  for (int i = t; i < ncnt; i += nthr) cnt[i] = 0u;
  grid.sync();

  // ---- phase 1: transform-fused face records + bucket counts ----
  if (t < BF) {
    int b = t / F;
    int f = t - b * F;
    int i0 = faces[f * 3 + 0];
    int i1 = faces[f * 3 + 1];
    int i2 = faces[f * 3 + 2];
    float c0n = camn[b * 3 + 0], c1n = camn[b * 3 + 1], c2n = camn[b * 3 + 2];
    float c0o = cam[b * 3 + 0], c1o = cam[b * 3 + 1], c2o = cam[b * 3 + 2];

    float x0, y0, z0, x1, y1, z1, x2, y2, z2;
    float u0, v0, u1, v1, u2, v2;
#define XFORM(idx, X, Y, Z, U, V)                          \
    {                                                      \
      const float* p = hv + (size_t)(b * N + (idx)) * 3;   \
      float X0 = p[0], X1 = p[1], X2 = p[2];               \
      float t0 = c0n * (X0 + c1n);                         \
      float t1 = c0n * (X1 + c2n);                         \
      float t2 = c0n * X2;                                 \
      X = clip11(t0);                                      \
      Y = clip11(-t1);                                     \
      Z = -t2 + 10.0f;                                     \
      float s0 = c0o * (X0 + c1o);                         \
      float s1 = c0o * (X1 + c2o);                         \
      U = clip11(s0);                                      \
      V = clip11(-s1);                                     \
    }
    XFORM(i0, x0, y0, z0, u0, v0)
    XFORM(i1, x1, y1, z1, u1, v1)
    XFORM(i2, x2, y2, z2, u2, v2)
#undef XFORM

    float e1x = x1 - x0;
    float e1y = y1 - y0;
    float e2x = x2 - x0;
    float e2y = y2 - y0;
    float d = (e1x * e2y) - (e2x * e1y);
    float inv;
    if (fabsf(d) > 1e-8f) {
      inv = 1.0f / d;                     // IEEE division
    } else {
      inv = __int_as_float(0x7fc00000);   // NaN -> inside test fails
    }
    float4* fq = fh4 + (size_t)t * 4;
    fq[0] = make_float4(fminf(x0, fminf(x1, x2)), fmaxf(x0, fmaxf(x1, x2)),
                        fminf(y0, fminf(y1, y2)), fmaxf(y0, fmaxf(y1, y2)));
    fq[1] = make_float4(x0, y0, e1x, e1y);
    fq[2] = make_float4(e2x, e2y, inv, z0);
    fq[3] = make_float4(z1, z2, 0.0f, 0.0f);

    float zmn = fminf(z0, fminf(z1, z2));
    int kb = (int)((zmn - ZLO) * ((float)K_BUCKETS / (ZHI - ZLO)));
    kb = min(max(kb, 0), K_BUCKETS - 1);
    bkt[t] = (uint)kb;
    atomicAdd(&cnt[b * K_BUCKETS + kb], 1u);

    float4* aq = fa4 + (size_t)t * 2;
    aq[0] = make_float4(u0, v0, u1, v1);
    aq[1] = make_float4(u2, v2, 0.0f, 0.0f);
  }
  grid.sync();

  // ---- phase 2: exclusive prefix over K_BUCKETS counts (block b per batch)
  __shared__ uint s[256];
  if ((int)blockIdx.x < B) {
    int b = blockIdx.x;
    const uint* c = cnt + (size_t)b * K_BUCKETS;
    uint* o = off + (size_t)b * K_BUCKETS;
    int tid = threadIdx.x;
    uint v[16];
    uint sum = 0;
#pragma unroll
    for (int k = 0; k < 16; ++k) { v[k] = c[tid * 16 + k]; sum += v[k]; }
    s[tid] = sum;
    __syncthreads();
    for (int dd = 1; dd < 256; dd <<= 1) {
      uint tt = (tid >= dd) ? s[tid - dd] : 0u;
      __syncthreads();
      s[tid] += tt;
      __syncthreads();
    }
    uint run = s[tid] - sum;   // exclusive
#pragma unroll
    for (int k = 0; k < 16; ++k) { o[tid * 16 + k] = run; run += v[k]; }
  }
  grid.sync();

  // ---- phase 3: scatter to z-sorted arrays ----
  if (t < BF) {
    int b = t / F;
    int f = t - b * F;
    uint kb = bkt[t];
    uint pos = atomicAdd(&off[b * K_BUCKETS + kb], 1u);
    const float4* sp = fh4 + (size_t)t * 4;
    float4 q0 = sp[0], q1 = sp[1], q2 = sp[2], q3 = sp[3];
    q3.z = __uint_as_float((uint)f);
    q3.w = (kb == 0u) ? -1e30f : (ZLO + (float)kb * ((ZHI - ZLO) / (float)K_BUCKETS));
    float4* d = s3 + ((size_t)b * F + pos) * 3;
    d[0] = q1; d[1] = q2; d[2] = q3;
    bboxs[(size_t)b * F + pos] = q0;
    if ((pos & 63u) == 0u) lbC[b * NCH64 + (pos >> 6)] = q3.w;
  }
}

// wave-autonomous raster: SEGUSED*B*1024 waves, 128-thr blocks (2 waves),
// one wave = 8x8-px tile (1 px/lane) x z-segment
__global__ void __launch_bounds__(128) k_raster(const float4* __restrict__ s3,
                                                const float4* __restrict__ bboxs,
                                                const float* __restrict__ lbC,
                                                ull* __restrict__ packed,
                                                int F, int NCH64, int B) {
#pragma clang fp contract(off)
  int w = blockIdx.x * 2 + (threadIdx.x >> 6);
  int lane = threadIdx.x & 63;
  int tilesPerSeg = B * 1024;
  int s = w / tilesPerSeg;              // segment-major: seg 0 launches first
  int rem = w - s * tilesPerSeg;
  int b = rem >> 10;
  int tile = rem & 1023;
  int tx = tile & 31, ty = tile >> 5;   // 32x32 tiles of 8x8 px
  int col = tx * 8 + (lane & 7);
  int row = ty * 8 + (lane >> 3);

  float px = (col + 0.5f) / 256.0f * 2.0f - 1.0f;
  float py = (row + 0.5f) / 256.0f * 2.0f - 1.0f;
  float txlo = (tx * 8 + 0.5f) / 256.0f * 2.0f - 1.0f - PAD;
  float txhi = (tx * 8 + 7.5f) / 256.0f * 2.0f - 1.0f + PAD;
  float tylo = (ty * 8 + 0.5f) / 256.0f * 2.0f - 1.0f - PAD;
  float tyhi = (ty * 8 + 7.5f) / 256.0f * 2.0f - 1.0f + PAD;

  const float4* __restrict__ s3B = s3 + (size_t)b * F * 3;
  const float4* __restrict__ bbB = bboxs + (size_t)b * F;
  const float* __restrict__ lbB = lbC + b * NCH64;
  size_t pix = ((size_t)b << 16) + (row << 8) + col;

  ull best = 0xFFFFFFFFFFFFFFFFull, pub = 0xFFFFFFFFFFFFFFFFull;

  int cps = (NCH64 + NSEG - 1) / NSEG;
  int ch0 = s * cps;
  int ch1 = min(NCH64, ch0 + cps);
  if (ch0 >= ch1) return;

  float4 bbCur = bbB[(size_t)(ch0 * 64 + lane)];   // prefetch first chunk

  for (int cg = ch0; cg < ch1; cg += GROUP) {
    // poll once per group: known = min(local best z, global z). Partial
    // publishes are mins over subsets -> valid upper bounds; NaN-safe:
    // no-candidate (NaN) makes the comparison false -> keep scanning.
    ull pk = __hip_atomic_load(packed + pix, __ATOMIC_RELAXED,
                               __HIP_MEMORY_SCOPE_AGENT);
    float kz = fminf(__uint_as_float((uint)(best >> 32)),
                     __uint_as_float((uint)(pk >> 32)));
    float lb = lbB[cg];   // lower-bounds zmin of all faces at index >= cg*64
    if (__all(lb >= kz + TOL)) break;

    int cend = min(cg + GROUP, ch1);
    for (int ch = cg; ch < cend; ++ch) {
      // issue next chunk's bbox load before this chunk's work (prefetch)
      int ni = (ch + 1 < ch1) ? ch + 1 : ch;
      float4 bbNxt = bbB[(size_t)(ni * 64 + lane)];

      int si = ch * 64 + lane;
      bool ok = (bbCur.x <= txhi && bbCur.y >= txlo &&
                 bbCur.z <= tyhi && bbCur.w >= tylo);
      float4 r1 = bbCur, r2 = bbCur, r3 = bbCur;   // defined defaults
      if (ok) {
        r1 = s3B[(size_t)si * 3 + 0];   // v0x v0y e1x e1y
        r2 = s3B[(size_t)si * 3 + 1];   // e2x e2y inv z0
        // SAT: separated if all padded-rect corners strictly outside one
        // triangle edge. NaN (degenerate) keeps face; inner test rejects it.
        float ax = r1.x, ay = r1.y;
        float e1x = r1.z, e1y = r1.w;
        float e2x = r2.x, e2y = r2.y;
        float sg = r2.z;
        float e3x = e2x - e1x, e3y = e2y - e1y;
        float bxx = ax + e1x, bxy = ay + e1y;
        float nx = -sg * e1y, ny = sg * e1x;
        float dotA = nx * ((nx > 0.0f ? txhi : txlo) - ax) +
                     ny * ((ny > 0.0f ? tyhi : tylo) - ay);
        nx = sg * e2y; ny = -sg * e2x;
        float dotB = nx * ((nx > 0.0f ? txhi : txlo) - ax) +
                     ny * ((ny > 0.0f ? tyhi : tylo) - ay);
        nx = -sg * e3y; ny = sg * e3x;
        float dotC = nx * ((nx > 0.0f ? txhi : txlo) - bxx) +
                     ny * ((ny > 0.0f ? tyhi : tylo) - bxy);
        ok = !(dotA < 0.0f) && !(dotB < 0.0f) && !(dotC < 0.0f);
      }
      if (ok) r3 = s3B[(size_t)si * 3 + 2];   // z1 z2 fo lb

      ull m = __ballot(ok);
      while (m) {
        int j = (int)__builtin_ctzll(m);
        m &= m - 1;
        // register broadcast from lane j (readlane -> SGPR, no memory)
        float v0x = RL(r1.x, j), v0y = RL(r1.y, j);
        float e1x = RL(r1.z, j), e1y = RL(r1.w, j);
        float e2x = RL(r2.x, j), e2y = RL(r2.y, j);
        float inv = RL(r2.z, j), z0 = RL(r2.w, j);
        float z1 = RL(r3.x, j), z2 = RL(r3.y, j);
        uint fo = (uint)__builtin_amdgcn_readlane((int)__float_as_uint(r3.z), j);
        float dpx = px - v0x;
        float dpy = py - v0y;
        float w1 = (dpx * e2y - e2x * dpy) * inv;
        float w2 = (e1x * dpy - dpx * e1y) * inv;
        float w0 = (1.0f - w1) - w2;
        bool inside = (w0 >= 0.0f) && (w1 >= 0.0f) && (w2 >= 0.0f);
        float z = (w0 * z0 + w1 * z1) + w2 * z2;
        ull cand = ((ull)__float_as_uint(z) << 32) | (ull)fo;
        // z > 0 always => float bits monotone => u64 compare is lex (z, f)
        best = (inside && cand < best) ? cand : best;
      }
      bbCur = bbNxt;
    }
    // publish improvements once per group (throttles atomic traffic)
    if (best < pub) { atomicMin(packed + pix, best); pub = best; }
  }
  if (best < pub) atomicMin(packed + pix, best);
}

__device__ __forceinline__ float fetchpix(const float* __restrict__ img, int base,
                                          float ixf, float iyf) {
  bool valid = (ixf >= 0.0f) && (ixf < 256.0f) && (iyf >= 0.0f) && (iyf < 256.0f);
  int ix = (int)fminf(255.0f, fmaxf(0.0f, ixf));
  int iy = (int)fminf(255.0f, fmaxf(0.0f, iyf));
  float v = img[base + iy * 256 + ix];
  return valid ? v : 0.0f;
}

__global__ void __launch_bounds__(256) k_sample(const float4* __restrict__ fh4,
                                                const float4* __restrict__ fa4,
                                                const ull* __restrict__ packed,
                                                const float* __restrict__ img,
                                                float* __restrict__ out,
                                                int F) {
#pragma clang fp contract(off)
  int t = blockIdx.x * 256 + threadIdx.x;   // over B*65536
  int b = t >> 16;
  int pix = t & 65535;
  int row = pix >> 8;
  int col = pix & 255;
  float px = (col + 0.5f) / 256.0f * 2.0f - 1.0f;
  float py = (row + 0.5f) / 256.0f * 2.0f - 1.0f;

  ull pk = packed[t];
  uint f = (uint)pk;
  float gx = 0.0f, gy = 0.0f;
  if (f != 0xFFFFFFFFu) {
    const float4* fq = fh4 + ((size_t)b * F + f) * 4;
    float4 q1 = fq[1];
    float4 q2 = fq[2];
    float dpx = px - q1.x;
    float dpy = py - q1.y;
    float w1 = (dpx * q2.y - q2.x * dpy) * q2.z;   // bit-identical to k_raster
    float w2 = (q1.z * dpy - dpx * q1.w) * q2.z;
    float w0 = (1.0f - w1) - w2;
    const float4* aq = fa4 + ((size_t)b * F + f) * 2;
    float4 a0 = aq[0];
    float4 a1 = aq[1];
    gx = (w0 * a0.x + w1 * a0.z) + w2 * a1.x;
    gy = (w0 * a0.y + w1 * a0.w) + w2 * a1.y;
  }

  // grid_sample (align_corners=False, zero pad), exact ref op order
  float x = (gx + 1.0f) * 0.5f * 256.0f - 0.5f;
  float y = (gy + 1.0f) * 0.5f * 256.0f - 0.5f;
  float x0f = floorf(x), y0f = floorf(y);
  float wx1 = x - x0f, wx0 = 1.0f - wx1;
  float wy1 = y - y0f, wy0 = 1.0f - wy1;

  for (int ch = 0; ch < 3; ++ch) {
    int base = (b * 3 + ch) * 65536;
    float f00 = fetchpix(img, base, x0f, y0f);
    float f10 = fetchpix(img, base, x0f + 1.0f, y0f);
    float f01 = fetchpix(img, base, x0f, y0f + 1.0f);
    float f11 = fetchpix(img, base, x0f + 1.0f, y0f + 1.0f);
    float A  = wy0 * ((wx0 * f00) + (wx1 * f10));
    float Bv = wy1 * ((wx0 * f01) + (wx1 * f11));
    out[base + pix] = A + Bv;
  }
}

extern "C" void kernel_launch(void* const* d_in, const int* in_sizes, int n_in,
                              void* d_out, int out_size, void* d_ws, size_t ws_size,
                              hipStream_t stream) {
  const int* faces  = (const int*)d_in[4];
  const float* cam  = (const float*)d_in[0];
  const float* hv   = (const float*)d_in[1];
  const float* img  = (const float*)d_in[2];
  const float* camn = (const float*)d_in[3];

  const int B = in_sizes[0] / 3;            // 2
  const int N = in_sizes[1] / (3 * B);      // 5120
  const int F = in_sizes[4] / 3;            // 10240
  const int NCH64 = (F + 63) / 64;          // 160
  const int P = 65536;

  char* wsb = (char*)d_ws;
  size_t ofs = 0;
  float4* fh4   = (float4*)(wsb + ofs); ofs += (size_t)B * F * 4 * sizeof(float4);
  float4* fa4   = (float4*)(wsb + ofs); ofs += (size_t)B * F * 2 * sizeof(float4);
  float4* s3    = (float4*)(wsb + ofs); ofs += (size_t)B * F * 3 * sizeof(float4);
  float4* bboxs = (float4*)(wsb + ofs); ofs += (size_t)B * F * sizeof(float4);
  uint* bkt = (uint*)(wsb + ofs); ofs += (size_t)B * F * 4;
  uint* cnt = (uint*)(wsb + ofs); ofs += (size_t)B * K_BUCKETS * 4;
  uint* off = (uint*)(wsb + ofs); ofs += (size_t)B * K_BUCKETS * 4;
  float* lbC = (float*)(wsb + ofs); ofs += (size_t)B * NCH64 * 4;
  ofs = (ofs + 255) & ~(size_t)255;
  ull* packed = (ull*)(wsb + ofs); ofs += (size_t)B * P * sizeof(ull);

  int np = B * P;
  int nf = B * F;
  int nblk = (nf + 255) / 256;   // 80 blocks, trivially co-resident

  {
    void* args[] = {(void*)&faces, (void*)&hv, (void*)&cam, (void*)&camn,
                    (void*)&fh4, (void*)&fa4, (void*)&bkt, (void*)&cnt,
                    (void*)&off, (void*)&s3, (void*)&bboxs, (void*)&lbC,
                    (void*)&packed, (void*)&np, (void*)&F, (void*)&N,
                    (void*)&B, (void*)&NCH64};
    hipLaunchCooperativeKernel((const void*)k_prep, dim3(nblk), dim3(256),
                               args, 0, stream);
  }

  const int cps = (NCH64 + NSEG - 1) / NSEG;          // 3
  const int segUsed = (NCH64 + cps - 1) / cps;        // 54 non-empty segments
  int nwaves = segUsed * B * 1024;
  k_raster<<<nwaves / 2, 128, 0, stream>>>(s3, bboxs, lbC, packed, F, NCH64, B);
  k_sample<<<(np + 255) / 256, 256, 0, stream>>>(fh4, fa4, packed, img, (float*)d_out, F);
}

// Round 22
// 116.943 us; speedup vs baseline: 1.0480x; 1.0480x over previous
//
#include <hip/hip_runtime.h>
#include <stdint.h>

typedef unsigned int uint;
typedef unsigned long long ull;

// B=2, N=5120, F=10240, H=W=256. Bit-exact fp32 replication of the reference
// (contract off, IEEE div). Pipeline:
//   memset(cnt=0) -> k_faces (transform fused, per-face records, zmin bucket
//   counts, packed-init folded) -> k_prefix -> k_scatter (z-sorted records +
//   bbox + per-64-chunk lb array) ->
//   k_raster: WAVE-AUTONOMOUS. One wave = one 8x8-px tile x ONE 64-face
//     chunk (NSEG=160 => cps=1; 160*B*1024 waves, 1 px/lane, no LDS, no
//     barriers). Each wave: poll packed + lb check -> exit or scan its chunk
//     (bbox+SAT cull, ballot, readlane-broadcast survivors, branchless test,
//     best = packed u64 (z_bits<<32|orig_f)) -> publish improvement.
//     Termination NaN-safe (no-candidate known=NaN -> compare false).
//   -> k_sample recomputes winner barycentrics bit-identically + bilinear.
// R22 = R20 + NSEG 64->160 (cps=1): the tail-splitting lever (3/3 wins:
// R14,R16,R17) pushed to its limit -- maximal straggler parallelism, late
// segs exit at first poll. R19/R21 lesson: device-scope sync primitives
// (acq_rel RMW, grid.sync) cost tens of us on non-coherent XCD L2s; stick
// to RELAXED polls + stream-ordered kernels.
// Winner = lexicographic (z, orig_f) min == reference chunked argmin.
// Sorted record s3 = 3 float4/face: {v0x,v0y,e1x,e1y} {e2x,e2y,inv,z0}
//                                   {z1,z2,bits(orig_f),lb}; bbox separate.

#define K_BUCKETS 4096
#define ZLO 0.0f
#define ZHI 20.0f
#define TOL 2.5e-4f      // >=50x the ~5e-6 fp slack (z is a convex comb.)
#define NSEG 160         // one 64-face chunk per wave (cps = 1)
#define PAD 0.004f       // conservative cull pad (>=100x fp slack)
#define GROUP 4          // poll/publish cadence (>= cps -> one poll per wave)

__device__ __forceinline__ float clip11(float t) {
  return fminf(1.0f, fmaxf(-1.0f, t));
}

__device__ __forceinline__ float RL(float v, int j) {
  return __uint_as_float((uint)__builtin_amdgcn_readlane((int)__float_as_uint(v), j));
}

__global__ void k_faces(const int* __restrict__ faces,
                        const float* __restrict__ hv,
                        const float* __restrict__ cam,
                        const float* __restrict__ camn,
                        float4* __restrict__ fh4,   // B*F*4 (orig order)
                        float4* __restrict__ fa4,   // B*F*2 (orig order)
                        uint* __restrict__ bkt,     // B*F
                        uint* __restrict__ cnt,     // B*K
                        ull* __restrict__ packed, int np,
                        int F, int N, int B) {
#pragma clang fp contract(off)
  int t = blockIdx.x * 256 + threadIdx.x;
  int nthr = gridDim.x * 256;
  // fold packed-init here (stream order makes it visible to k_raster)
  for (int i = t; i < np; i += nthr) packed[i] = 0xFFFFFFFFFFFFFFFFull;
  if (t >= B * F) return;
  int b = t / F;
  int f = t - b * F;
  int i0 = faces[f * 3 + 0];
  int i1 = faces[f * 3 + 1];
  int i2 = faces[f * 3 + 2];
  float c0n = camn[b * 3 + 0], c1n = camn[b * 3 + 1], c2n = camn[b * 3 + 2];
  float c0o = cam[b * 3 + 0], c1o = cam[b * 3 + 1], c2o = cam[b * 3 + 2];

  float x0, y0, z0, x1, y1, z1, x2, y2, z2;
  float u0, v0, u1, v1, u2, v2;
#define XFORM(idx, X, Y, Z, U, V)                          \
  {                                                        \
    const float* p = hv + (size_t)(b * N + (idx)) * 3;     \
    float X0 = p[0], X1 = p[1], X2 = p[2];                 \
    float t0 = c0n * (X0 + c1n);                           \
    float t1 = c0n * (X1 + c2n);                           \
    float t2 = c0n * X2;                                   \
    X = clip11(t0);                                        \
    Y = clip11(-t1);                                       \
    Z = -t2 + 10.0f;                                       \
    float s0 = c0o * (X0 + c1o);                           \
    float s1 = c0o * (X1 + c2o);                           \
    U = clip11(s0);                                        \
    V = clip11(-s1);                                       \
  }
  XFORM(i0, x0, y0, z0, u0, v0)
  XFORM(i1, x1, y1, z1, u1, v1)
  XFORM(i2, x2, y2, z2, u2, v2)
#undef XFORM

  float e1x = x1 - x0;
  float e1y = y1 - y0;
  float e2x = x2 - x0;
  float e2y = y2 - y0;
  float d = (e1x * e2y) - (e2x * e1y);
  float inv;
  if (fabsf(d) > 1e-8f) {
    inv = 1.0f / d;                     // IEEE division
  } else {
    inv = __int_as_float(0x7fc00000);   // NaN -> inside test fails
  }
  float4* fq = fh4 + (size_t)t * 4;
  fq[0] = make_float4(fminf(x0, fminf(x1, x2)), fmaxf(x0, fmaxf(x1, x2)),
                      fminf(y0, fminf(y1, y2)), fmaxf(y0, fmaxf(y1, y2)));
  fq[1] = make_float4(x0, y0, e1x, e1y);
  fq[2] = make_float4(e2x, e2y, inv, z0);
  fq[3] = make_float4(z1, z2, 0.0f, 0.0f);

  float zmn = fminf(z0, fminf(z1, z2));
  int kb = (int)((zmn - ZLO) * ((float)K_BUCKETS / (ZHI - ZLO)));
  kb = min(max(kb, 0), K_BUCKETS - 1);
  bkt[t] = (uint)kb;
  atomicAdd(&cnt[b * K_BUCKETS + kb], 1u);

  float4* aq = fa4 + (size_t)t * 2;
  aq[0] = make_float4(u0, v0, u1, v1);
  aq[1] = make_float4(u2, v2, 0.0f, 0.0f);
}

// one block per batch; exclusive prefix over K_BUCKETS counts
__global__ void __launch_bounds__(1024) k_prefix(const uint* __restrict__ cnt,
                                                 uint* __restrict__ off) {
  __shared__ uint s[1024];
  int b = blockIdx.x;
  const uint* c = cnt + (size_t)b * K_BUCKETS;
  uint* o = off + (size_t)b * K_BUCKETS;
  int tid = threadIdx.x;
  uint v0 = c[tid * 4 + 0], v1 = c[tid * 4 + 1], v2 = c[tid * 4 + 2], v3 = c[tid * 4 + 3];
  uint sum = v0 + v1 + v2 + v3;
  s[tid] = sum;
  __syncthreads();
  for (int d = 1; d < 1024; d <<= 1) {
    uint t = (tid >= d) ? s[tid - d] : 0u;
    __syncthreads();
    s[tid] += t;
    __syncthreads();
  }
  uint run = s[tid] - sum;   // exclusive
  o[tid * 4 + 0] = run; run += v0;
  o[tid * 4 + 1] = run; run += v1;
  o[tid * 4 + 2] = run; run += v2;
  o[tid * 4 + 3] = run;
}

__global__ void k_scatter(const float4* __restrict__ fh4,
                          const uint* __restrict__ bkt,
                          uint* __restrict__ off,       // consumed as cursor
                          float4* __restrict__ s3,      // B*F*3 sorted records
                          float4* __restrict__ bboxs,   // B*F sorted bboxes
                          float* __restrict__ lbC,      // B*NCH64 chunk lbs
                          int F, int NCH64, int B) {
  int t = blockIdx.x * 256 + threadIdx.x;
  if (t >= B * F) return;
  int b = t / F;
  int f = t - b * F;
  uint kb = bkt[t];
  uint pos = atomicAdd(&off[b * K_BUCKETS + kb], 1u);
  const float4* s = fh4 + (size_t)t * 4;
  float4 q0 = s[0], q1 = s[1], q2 = s[2], q3 = s[3];
  q3.z = __uint_as_float((uint)f);
  q3.w = (kb == 0u) ? -1e30f : (ZLO + (float)kb * ((ZHI - ZLO) / (float)K_BUCKETS));
  float4* d = s3 + ((size_t)b * F + pos) * 3;
  d[0] = q1; d[1] = q2; d[2] = q3;
  bboxs[(size_t)b * F + pos] = q0;
  if ((pos & 63u) == 0u) lbC[b * NCH64 + (pos >> 6)] = q3.w;
}

// wave-autonomous raster: segUsed*B*1024 waves, 128-thr blocks (2 waves),
// one wave = 8x8-px tile (1 px/lane) x one 64-face chunk (cps = 1)
__global__ void __launch_bounds__(128) k_raster(const float4* __restrict__ s3,
                                                const float4* __restrict__ bboxs,
                                                const float* __restrict__ lbC,
                                                ull* __restrict__ packed,
                                                int F, int NCH64, int B) {
#pragma clang fp contract(off)
  int w = blockIdx.x * 2 + (threadIdx.x >> 6);
  int lane = threadIdx.x & 63;
  int tilesPerSeg = B * 1024;
  int s = w / tilesPerSeg;              // segment-major: seg 0 launches first
  int rem = w - s * tilesPerSeg;
  int b = rem >> 10;
  int tile = rem & 1023;
  int tx = tile & 31, ty = tile >> 5;   // 32x32 tiles of 8x8 px
  int col = tx * 8 + (lane & 7);
  int row = ty * 8 + (lane >> 3);

  float px = (col + 0.5f) / 256.0f * 2.0f - 1.0f;
  float py = (row + 0.5f) / 256.0f * 2.0f - 1.0f;
  float txlo = (tx * 8 + 0.5f) / 256.0f * 2.0f - 1.0f - PAD;
  float txhi = (tx * 8 + 7.5f) / 256.0f * 2.0f - 1.0f + PAD;
  float tylo = (ty * 8 + 0.5f) / 256.0f * 2.0f - 1.0f - PAD;
  float tyhi = (ty * 8 + 7.5f) / 256.0f * 2.0f - 1.0f + PAD;

  const float4* __restrict__ s3B = s3 + (size_t)b * F * 3;
  const float4* __restrict__ bbB = bboxs + (size_t)b * F;
  const float* __restrict__ lbB = lbC + b * NCH64;
  size_t pix = ((size_t)b << 16) + (row << 8) + col;

  ull best = 0xFFFFFFFFFFFFFFFFull, pub = 0xFFFFFFFFFFFFFFFFull;

  int cps = (NCH64 + NSEG - 1) / NSEG;   // == 1
  int ch0 = s * cps;
  int ch1 = min(NCH64, ch0 + cps);
  if (ch0 >= ch1) return;

  float4 bbCur = bbB[(size_t)(ch0 * 64 + lane)];   // prefetch first chunk

  for (int cg = ch0; cg < ch1; cg += GROUP) {
    // poll once per group: known = min(local best z, global z). Partial
    // publishes are mins over subsets -> valid upper bounds; NaN-safe:
    // no-candidate (NaN) makes the comparison false -> keep scanning.
    ull pk = __hip_atomic_load(packed + pix, __ATOMIC_RELAXED,
                               __HIP_MEMORY_SCOPE_AGENT);
    float kz = fminf(__uint_as_float((uint)(best >> 32)),
                     __uint_as_float((uint)(pk >> 32)));
    float lb = lbB[cg];   // lower-bounds zmin of all faces at index >= cg*64
    if (__all(lb >= kz + TOL)) break;

    int cend = min(cg + GROUP, ch1);
    for (int ch = cg; ch < cend; ++ch) {
      // issue next chunk's bbox load before this chunk's work (prefetch)
      int ni = (ch + 1 < ch1) ? ch + 1 : ch;
      float4 bbNxt = bbB[(size_t)(ni * 64 + lane)];

      int si = ch * 64 + lane;
      bool ok = (bbCur.x <= txhi && bbCur.y >= txlo &&
                 bbCur.z <= tyhi && bbCur.w >= tylo);
      float4 r1 = bbCur, r2 = bbCur, r3 = bbCur;   // defined defaults
      if (ok) {
        r1 = s3B[(size_t)si * 3 + 0];   // v0x v0y e1x e1y
        r2 = s3B[(size_t)si * 3 + 1];   // e2x e2y inv z0
        // SAT: separated if all padded-rect corners strictly outside one
        // triangle edge. NaN (degenerate) keeps face; inner test rejects it.
        float ax = r1.x, ay = r1.y;
        float e1x = r1.z, e1y = r1.w;
        float e2x = r2.x, e2y = r2.y;
        float sg = r2.z;
        float e3x = e2x - e1x, e3y = e2y - e1y;
        float bxx = ax + e1x, bxy = ay + e1y;
        float nx = -sg * e1y, ny = sg * e1x;
        float dotA = nx * ((nx > 0.0f ? txhi : txlo) - ax) +
                     ny * ((ny > 0.0f ? tyhi : tylo) - ay);
        nx = sg * e2y; ny = -sg * e2x;
        float dotB = nx * ((nx > 0.0f ? txhi : txlo) - ax) +
                     ny * ((ny > 0.0f ? tyhi : tylo) - ay);
        nx = -sg * e3y; ny = sg * e3x;
        float dotC = nx * ((nx > 0.0f ? txhi : txlo) - bxx) +
                     ny * ((ny > 0.0f ? tyhi : tylo) - bxy);
        ok = !(dotA < 0.0f) && !(dotB < 0.0f) && !(dotC < 0.0f);
      }
      if (ok) r3 = s3B[(size_t)si * 3 + 2];   // z1 z2 fo lb

      ull m = __ballot(ok);
      while (m) {
        int j = (int)__builtin_ctzll(m);
        m &= m - 1;
        // register broadcast from lane j (readlane -> SGPR, no memory)
        float v0x = RL(r1.x, j), v0y = RL(r1.y, j);
        float e1x = RL(r1.z, j), e1y = RL(r1.w, j);
        float e2x = RL(r2.x, j), e2y = RL(r2.y, j);
        float inv = RL(r2.z, j), z0 = RL(r2.w, j);
        float z1 = RL(r3.x, j), z2 = RL(r3.y, j);
        uint fo = (uint)__builtin_amdgcn_readlane((int)__float_as_uint(r3.z), j);
        float dpx = px - v0x;
        float dpy = py - v0y;
        float w1 = (dpx * e2y - e2x * dpy) * inv;
        float w2 = (e1x * dpy - dpx * e1y) * inv;
        float w0 = (1.0f - w1) - w2;
        bool inside = (w0 >= 0.0f) && (w1 >= 0.0f) && (w2 >= 0.0f);
        float z = (w0 * z0 + w1 * z1) + w2 * z2;
        ull cand = ((ull)__float_as_uint(z) << 32) | (ull)fo;
        // z > 0 always => float bits monotone => u64 compare is lex (z, f)
        best = (inside && cand < best) ? cand : best;
      }
      bbCur = bbNxt;
    }
    // publish improvements once per group (throttles atomic traffic)
    if (best < pub) { atomicMin(packed + pix, best); pub = best; }
  }
  if (best < pub) atomicMin(packed + pix, best);
}

__device__ __forceinline__ float fetchpix(const float* __restrict__ img, int base,
                                          float ixf, float iyf) {
  bool valid = (ixf >= 0.0f) && (ixf < 256.0f) && (iyf >= 0.0f) && (iyf < 256.0f);
  int ix = (int)fminf(255.0f, fmaxf(0.0f, ixf));
  int iy = (int)fminf(255.0f, fmaxf(0.0f, iyf));
  float v = img[base + iy * 256 + ix];
  return valid ? v : 0.0f;
}

__global__ void __launch_bounds__(256) k_sample(const float4* __restrict__ fh4,
                                                const float4* __restrict__ fa4,
                                                const ull* __restrict__ packed,
                                                const float* __restrict__ img,
                                                float* __restrict__ out,
                                                int F) {
#pragma clang fp contract(off)
  int t = blockIdx.x * 256 + threadIdx.x;   // over B*65536
  int b = t >> 16;
  int pix = t & 65535;
  int row = pix >> 8;
  int col = pix & 255;
  float px = (col + 0.5f) / 256.0f * 2.0f - 1.0f;
  float py = (row + 0.5f) / 256.0f * 2.0f - 1.0f;

  ull pk = packed[t];
  uint f = (uint)pk;
  float gx = 0.0f, gy = 0.0f;
  if (f != 0xFFFFFFFFu) {
    const float4* fq = fh4 + ((size_t)b * F + f) * 4;
    float4 q1 = fq[1];
    float4 q2 = fq[2];
    float dpx = px - q1.x;
    float dpy = py - q1.y;
    float w1 = (dpx * q2.y - q2.x * dpy) * q2.z;   // bit-identical to k_raster
    float w2 = (q1.z * dpy - dpx * q1.w) * q2.z;
    float w0 = (1.0f - w1) - w2;
    const float4* aq = fa4 + ((size_t)b * F + f) * 2;
    float4 a0 = aq[0];
    float4 a1 = aq[1];
    gx = (w0 * a0.x + w1 * a0.z) + w2 * a1.x;
    gy = (w0 * a0.y + w1 * a0.w) + w2 * a1.y;
  }

  // grid_sample (align_corners=False, zero pad), exact ref op order
  float x = (gx + 1.0f) * 0.5f * 256.0f - 0.5f;
  float y = (gy + 1.0f) * 0.5f * 256.0f - 0.5f;
  float x0f = floorf(x), y0f = floorf(y);
  float wx1 = x - x0f, wx0 = 1.0f - wx1;
  float wy1 = y - y0f, wy0 = 1.0f - wy1;

  for (int ch = 0; ch < 3; ++ch) {
    int base = (b * 3 + ch) * 65536;
    float f00 = fetchpix(img, base, x0f, y0f);
    float f10 = fetchpix(img, base, x0f + 1.0f, y0f);
    float f01 = fetchpix(img, base, x0f, y0f + 1.0f);
    float f11 = fetchpix(img, base, x0f + 1.0f, y0f + 1.0f);
    float A  = wy0 * ((wx0 * f00) + (wx1 * f10));
    float Bv = wy1 * ((wx0 * f01) + (wx1 * f11));
    out[base + pix] = A + Bv;
  }
}

extern "C" void kernel_launch(void* const* d_in, const int* in_sizes, int n_in,
                              void* d_out, int out_size, void* d_ws, size_t ws_size,
                              hipStream_t stream) {
  const float* cam  = (const float*)d_in[0];
  const float* hv   = (const float*)d_in[1];
  const float* img  = (const float*)d_in[2];
  const float* camn = (const float*)d_in[3];
  const int* faces  = (const int*)d_in[4];

  const int B = in_sizes[0] / 3;            // 2
  const int N = in_sizes[1] / (3 * B);      // 5120
  const int F = in_sizes[4] / 3;            // 10240
  const int NCH64 = (F + 63) / 64;          // 160
  const int P = 65536;

  char* wsb = (char*)d_ws;
  size_t ofs = 0;
  float4* fh4   = (float4*)(wsb + ofs); ofs += (size_t)B * F * 4 * sizeof(float4);
  float4* fa4   = (float4*)(wsb + ofs); ofs += (size_t)B * F * 2 * sizeof(float4);
  float4* s3    = (float4*)(wsb + ofs); ofs += (size_t)B * F * 3 * sizeof(float4);
  float4* bboxs = (float4*)(wsb + ofs); ofs += (size_t)B * F * sizeof(float4);
  uint* bkt = (uint*)(wsb + ofs); ofs += (size_t)B * F * 4;
  uint* cnt = (uint*)(wsb + ofs); ofs += (size_t)B * K_BUCKETS * 4;
  uint* off = (uint*)(wsb + ofs); ofs += (size_t)B * K_BUCKETS * 4;
  float* lbC = (float*)(wsb + ofs); ofs += (size_t)B * NCH64 * 4;
  ofs = (ofs + 255) & ~(size_t)255;
  ull* packed = (ull*)(wsb + ofs); ofs += (size_t)B * P * sizeof(ull);

  int np = B * P;
  hipMemsetAsync(cnt, 0, (size_t)B * K_BUCKETS * 4, stream);
  int nf = B * F;
  k_faces<<<(nf + 255) / 256, 256, 0, stream>>>(faces, hv, cam, camn,
                                                fh4, fa4, bkt, cnt,
                                                packed, np, F, N, B);
  k_prefix<<<B, 1024, 0, stream>>>(cnt, off);
  k_scatter<<<(nf + 255) / 256, 256, 0, stream>>>(fh4, bkt, off, s3, bboxs,
                                                  lbC, F, NCH64, B);
  const int cps = (NCH64 + NSEG - 1) / NSEG;          // 1
  const int segUsed = (NCH64 + cps - 1) / cps;        // 160
  int nwaves = segUsed * B * 1024;
  k_raster<<<nwaves / 2, 128, 0, stream>>>(s3, bboxs, lbC, packed, F, NCH64, B);
  k_sample<<<(np + 255) / 256, 256, 0, stream>>>(fh4, fa4, packed, img, (float*)d_out, F);
}

// Round 23
// 90.615 us; speedup vs baseline: 1.3526x; 1.2906x over previous
//
#include <hip/hip_runtime.h>
#include <stdint.h>

typedef unsigned int uint;
typedef unsigned long long ull;

// B=2, N=5120, F=10240, H=W=256. Bit-exact fp32 replication of the reference
// (contract off, IEEE div). Pipeline:
//   memset(cnt=0) -> k_faces (transform fused, per-face records, zmin bucket
//   counts, packed-init folded) -> k_prefix -> k_scatter (z-sorted records +
//   bbox + per-64-chunk lb array) ->
//   k_raster: WAVE-AUTONOMOUS. One wave = one 8x8-px tile x z-segment
//     (54*B*1024 waves, cps=3, 1 px/lane, no LDS, no barriers). Per 64-face
//     chunk: lane i culls face (prefetched bbox + SAT), ballot; iterate set
//     bits: readlane-broadcast 11 face scalars, branchless test, best =
//     packed u64 (z_bits<<32 | orig_f). Poll packed + publish best once per
//     GROUP chunks; R23: ALSO re-check lb vs (local best, polled) before
//     every chunk (cheap register check) so a wave whose chunk-0 winner
//     covers all 64 px skips chunks 1-2. Exit when __all(lb >= known + TOL)
//     [NaN-safe: no-candidate known=NaN -> comparison false -> keep going].
//   -> k_sample recomputes winner barycentrics bit-identically + bilinear.
// R22 lesson: cps=1 destroys local-best accumulation (work grew 48->81us);
// R19/R21 lesson: device-scope sync primitives cost tens of us on
// non-coherent XCD L2s. Winner = lexicographic (z, orig_f) min == reference
// chunked argmin (order-independent).
// Sorted record s3 = 3 float4/face: {v0x,v0y,e1x,e1y} {e2x,e2y,inv,z0}
//                                   {z1,z2,bits(orig_f),lb}; bbox separate.

#define K_BUCKETS 4096
#define ZLO 0.0f
#define ZHI 20.0f
#define TOL 2.5e-4f      // >=50x the ~5e-6 fp slack (z is a convex comb.)
#define NSEG 64          // z-segmentation granularity (cps = ceil(160/64) = 3)
#define PAD 0.004f       // conservative cull pad (>=100x fp slack)
#define GROUP 4          // chunks (of 64 faces) between poll/publish

__device__ __forceinline__ float clip11(float t) {
  return fminf(1.0f, fmaxf(-1.0f, t));
}

__device__ __forceinline__ float RL(float v, int j) {
  return __uint_as_float((uint)__builtin_amdgcn_readlane((int)__float_as_uint(v), j));
}

__global__ void k_faces(const int* __restrict__ faces,
                        const float* __restrict__ hv,
                        const float* __restrict__ cam,
                        const float* __restrict__ camn,
                        float4* __restrict__ fh4,   // B*F*4 (orig order)
                        float4* __restrict__ fa4,   // B*F*2 (orig order)
                        uint* __restrict__ bkt,     // B*F
                        uint* __restrict__ cnt,     // B*K
                        ull* __restrict__ packed, int np,
                        int F, int N, int B) {
#pragma clang fp contract(off)
  int t = blockIdx.x * 256 + threadIdx.x;
  int nthr = gridDim.x * 256;
  // fold packed-init here (stream order makes it visible to k_raster)
  for (int i = t; i < np; i += nthr) packed[i] = 0xFFFFFFFFFFFFFFFFull;
  if (t >= B * F) return;
  int b = t / F;
  int f = t - b * F;
  int i0 = faces[f * 3 + 0];
  int i1 = faces[f * 3 + 1];
  int i2 = faces[f * 3 + 2];
  float c0n = camn[b * 3 + 0], c1n = camn[b * 3 + 1], c2n = camn[b * 3 + 2];
  float c0o = cam[b * 3 + 0], c1o = cam[b * 3 + 1], c2o = cam[b * 3 + 2];

  float x0, y0, z0, x1, y1, z1, x2, y2, z2;
  float u0, v0, u1, v1, u2, v2;
#define XFORM(idx, X, Y, Z, U, V)                          \
  {                                                        \
    const float* p = hv + (size_t)(b * N + (idx)) * 3;     \
    float X0 = p[0], X1 = p[1], X2 = p[2];                 \
    float t0 = c0n * (X0 + c1n);                           \
    float t1 = c0n * (X1 + c2n);                           \
    float t2 = c0n * X2;                                   \
    X = clip11(t0);                                        \
    Y = clip11(-t1);                                       \
    Z = -t2 + 10.0f;                                       \
    float s0 = c0o * (X0 + c1o);                           \
    float s1 = c0o * (X1 + c2o);                           \
    U = clip11(s0);                                        \
    V = clip11(-s1);                                       \
  }
  XFORM(i0, x0, y0, z0, u0, v0)
  XFORM(i1, x1, y1, z1, u1, v1)
  XFORM(i2, x2, y2, z2, u2, v2)
#undef XFORM

  float e1x = x1 - x0;
  float e1y = y1 - y0;
  float e2x = x2 - x0;
  float e2y = y2 - y0;
  float d = (e1x * e2y) - (e2x * e1y);
  float inv;
  if (fabsf(d) > 1e-8f) {
    inv = 1.0f / d;                     // IEEE division
  } else {
    inv = __int_as_float(0x7fc00000);   // NaN -> inside test fails
  }
  float4* fq = fh4 + (size_t)t * 4;
  fq[0] = make_float4(fminf(x0, fminf(x1, x2)), fmaxf(x0, fmaxf(x1, x2)),
                      fminf(y0, fminf(y1, y2)), fmaxf(y0, fmaxf(y1, y2)));
  fq[1] = make_float4(x0, y0, e1x, e1y);
  fq[2] = make_float4(e2x, e2y, inv, z0);
  fq[3] = make_float4(z1, z2, 0.0f, 0.0f);

  float zmn = fminf(z0, fminf(z1, z2));
  int kb = (int)((zmn - ZLO) * ((float)K_BUCKETS / (ZHI - ZLO)));
  kb = min(max(kb, 0), K_BUCKETS - 1);
  bkt[t] = (uint)kb;
  atomicAdd(&cnt[b * K_BUCKETS + kb], 1u);

  float4* aq = fa4 + (size_t)t * 2;
  aq[0] = make_float4(u0, v0, u1, v1);
  aq[1] = make_float4(u2, v2, 0.0f, 0.0f);
}

// one block per batch; exclusive prefix over K_BUCKETS counts
__global__ void __launch_bounds__(1024) k_prefix(const uint* __restrict__ cnt,
                                                 uint* __restrict__ off) {
  __shared__ uint s[1024];
  int b = blockIdx.x;
  const uint* c = cnt + (size_t)b * K_BUCKETS;
  uint* o = off + (size_t)b * K_BUCKETS;
  int tid = threadIdx.x;
  uint v0 = c[tid * 4 + 0], v1 = c[tid * 4 + 1], v2 = c[tid * 4 + 2], v3 = c[tid * 4 + 3];
  uint sum = v0 + v1 + v2 + v3;
  s[tid] = sum;
  __syncthreads();
  for (int d = 1; d < 1024; d <<= 1) {
    uint t = (tid >= d) ? s[tid - d] : 0u;
    __syncthreads();
    s[tid] += t;
    __syncthreads();
  }
  uint run = s[tid] - sum;   // exclusive
  o[tid * 4 + 0] = run; run += v0;
  o[tid * 4 + 1] = run; run += v1;
  o[tid * 4 + 2] = run; run += v2;
  o[tid * 4 + 3] = run;
}

__global__ void k_scatter(const float4* __restrict__ fh4,
                          const uint* __restrict__ bkt,
                          uint* __restrict__ off,       // consumed as cursor
                          float4* __restrict__ s3,      // B*F*3 sorted records
                          float4* __restrict__ bboxs,   // B*F sorted bboxes
                          float* __restrict__ lbC,      // B*NCH64 chunk lbs
                          int F, int NCH64, int B) {
  int t = blockIdx.x * 256 + threadIdx.x;
  if (t >= B * F) return;
  int b = t / F;
  int f = t - b * F;
  uint kb = bkt[t];
  uint pos = atomicAdd(&off[b * K_BUCKETS + kb], 1u);
  const float4* s = fh4 + (size_t)t * 4;
  float4 q0 = s[0], q1 = s[1], q2 = s[2], q3 = s[3];
  q3.z = __uint_as_float((uint)f);
  q3.w = (kb == 0u) ? -1e30f : (ZLO + (float)kb * ((ZHI - ZLO) / (float)K_BUCKETS));
  float4* d = s3 + ((size_t)b * F + pos) * 3;
  d[0] = q1; d[1] = q2; d[2] = q3;
  bboxs[(size_t)b * F + pos] = q0;
  if ((pos & 63u) == 0u) lbC[b * NCH64 + (pos >> 6)] = q3.w;
}

// wave-autonomous raster: segUsed*B*1024 waves, 128-thr blocks (2 waves),
// one wave = 8x8-px tile (1 px/lane) x z-segment (cps = 3)
__global__ void __launch_bounds__(128) k_raster(const float4* __restrict__ s3,
                                                const float4* __restrict__ bboxs,
                                                const float* __restrict__ lbC,
                                                ull* __restrict__ packed,
                                                int F, int NCH64, int B) {
#pragma clang fp contract(off)
  int w = blockIdx.x * 2 + (threadIdx.x >> 6);
  int lane = threadIdx.x & 63;
  int tilesPerSeg = B * 1024;
  int s = w / tilesPerSeg;              // segment-major: seg 0 launches first
  int rem = w - s * tilesPerSeg;
  int b = rem >> 10;
  int tile = rem & 1023;
  int tx = tile & 31, ty = tile >> 5;   // 32x32 tiles of 8x8 px
  int col = tx * 8 + (lane & 7);
  int row = ty * 8 + (lane >> 3);

  float px = (col + 0.5f) / 256.0f * 2.0f - 1.0f;
  float py = (row + 0.5f) / 256.0f * 2.0f - 1.0f;
  float txlo = (tx * 8 + 0.5f) / 256.0f * 2.0f - 1.0f - PAD;
  float txhi = (tx * 8 + 7.5f) / 256.0f * 2.0f - 1.0f + PAD;
  float tylo = (ty * 8 + 0.5f) / 256.0f * 2.0f - 1.0f - PAD;
  float tyhi = (ty * 8 + 7.5f) / 256.0f * 2.0f - 1.0f + PAD;

  const float4* __restrict__ s3B = s3 + (size_t)b * F * 3;
  const float4* __restrict__ bbB = bboxs + (size_t)b * F;
  const float* __restrict__ lbB = lbC + b * NCH64;
  size_t pix = ((size_t)b << 16) + (row << 8) + col;

  ull best = 0xFFFFFFFFFFFFFFFFull, pub = 0xFFFFFFFFFFFFFFFFull;

  int cps = (NCH64 + NSEG - 1) / NSEG;   // 3
  int ch0 = s * cps;
  int ch1 = min(NCH64, ch0 + cps);
  if (ch0 >= ch1) return;

  float4 bbCur = bbB[(size_t)(ch0 * 64 + lane)];   // prefetch first chunk
  bool done = false;

  for (int cg = ch0; cg < ch1 && !done; cg += GROUP) {
    // poll once per group: pz = global best z (stale-conservative).
    ull pk = __hip_atomic_load(packed + pix, __ATOMIC_RELAXED,
                               __HIP_MEMORY_SCOPE_AGENT);
    float pz = __uint_as_float((uint)(pk >> 32));

    int cend = min(cg + GROUP, ch1);
    for (int ch = cg; ch < cend; ++ch) {
      // per-chunk termination: known = min(fresh local best z, polled pz).
      // NaN-safe (no candidate -> NaN -> compare false -> keep scanning).
      float kz = fminf(__uint_as_float((uint)(best >> 32)), pz);
      float lb = lbB[ch];   // lower-bounds zmin of faces at index >= ch*64
      if (__all(lb >= kz + TOL)) { done = true; break; }

      // issue next chunk's bbox load before this chunk's work (prefetch)
      int ni = (ch + 1 < ch1) ? ch + 1 : ch;
      float4 bbNxt = bbB[(size_t)(ni * 64 + lane)];

      int si = ch * 64 + lane;
      bool ok = (bbCur.x <= txhi && bbCur.y >= txlo &&
                 bbCur.z <= tyhi && bbCur.w >= tylo);
      float4 r1 = bbCur, r2 = bbCur, r3 = bbCur;   // defined defaults
      if (ok) {
        r1 = s3B[(size_t)si * 3 + 0];   // v0x v0y e1x e1y
        r2 = s3B[(size_t)si * 3 + 1];   // e2x e2y inv z0
        // SAT: separated if all padded-rect corners strictly outside one
        // triangle edge. NaN (degenerate) keeps face; inner test rejects it.
        float ax = r1.x, ay = r1.y;
        float e1x = r1.z, e1y = r1.w;
        float e2x = r2.x, e2y = r2.y;
        float sg = r2.z;
        float e3x = e2x - e1x, e3y = e2y - e1y;
        float bxx = ax + e1x, bxy = ay + e1y;
        float nx = -sg * e1y, ny = sg * e1x;
        float dotA = nx * ((nx > 0.0f ? txhi : txlo) - ax) +
                     ny * ((ny > 0.0f ? tyhi : tylo) - ay);
        nx = sg * e2y; ny = -sg * e2x;
        float dotB = nx * ((nx > 0.0f ? txhi : txlo) - ax) +
                     ny * ((ny > 0.0f ? tyhi : tylo) - ay);
        nx = -sg * e3y; ny = sg * e3x;
        float dotC = nx * ((nx > 0.0f ? txhi : txlo) - bxx) +
                     ny * ((ny > 0.0f ? tyhi : tylo) - bxy);
        ok = !(dotA < 0.0f) && !(dotB < 0.0f) && !(dotC < 0.0f);
      }
      if (ok) r3 = s3B[(size_t)si * 3 + 2];   // z1 z2 fo lb

      ull m = __ballot(ok);
      while (m) {
        int j = (int)__builtin_ctzll(m);
        m &= m - 1;
        // register broadcast from lane j (readlane -> SGPR, no memory)
        float v0x = RL(r1.x, j), v0y = RL(r1.y, j);
        float e1x = RL(r1.z, j), e1y = RL(r1.w, j);
        float e2x = RL(r2.x, j), e2y = RL(r2.y, j);
        float inv = RL(r2.z, j), z0 = RL(r2.w, j);
        float z1 = RL(r3.x, j), z2 = RL(r3.y, j);
        uint fo = (uint)__builtin_amdgcn_readlane((int)__float_as_uint(r3.z), j);
        float dpx = px - v0x;
        float dpy = py - v0y;
        float w1 = (dpx * e2y - e2x * dpy) * inv;
        float w2 = (e1x * dpy - dpx * e1y) * inv;
        float w0 = (1.0f - w1) - w2;
        bool inside = (w0 >= 0.0f) && (w1 >= 0.0f) && (w2 >= 0.0f);
        float z = (w0 * z0 + w1 * z1) + w2 * z2;
        ull cand = ((ull)__float_as_uint(z) << 32) | (ull)fo;
        // z > 0 always => float bits monotone => u64 compare is lex (z, f)
        best = (inside && cand < best) ? cand : best;
      }
      bbCur = bbNxt;
    }
    // publish improvements once per group (throttles atomic traffic)
    if (best < pub) { atomicMin(packed + pix, best); pub = best; }
  }
  if (best < pub) atomicMin(packed + pix, best);
}

__device__ __forceinline__ float fetchpix(const float* __restrict__ img, int base,
                                          float ixf, float iyf) {
  bool valid = (ixf >= 0.0f) && (ixf < 256.0f) && (iyf >= 0.0f) && (iyf < 256.0f);
  int ix = (int)fminf(255.0f, fmaxf(0.0f, ixf));
  int iy = (int)fminf(255.0f, fmaxf(0.0f, iyf));
  float v = img[base + iy * 256 + ix];
  return valid ? v : 0.0f;
}

__global__ void __launch_bounds__(256) k_sample(const float4* __restrict__ fh4,
                                                const float4* __restrict__ fa4,
                                                const ull* __restrict__ packed,
                                                const float* __restrict__ img,
                                                float* __restrict__ out,
                                                int F) {
#pragma clang fp contract(off)
  int t = blockIdx.x * 256 + threadIdx.x;   // over B*65536
  int b = t >> 16;
  int pix = t & 65535;
  int row = pix >> 8;
  int col = pix & 255;
  float px = (col + 0.5f) / 256.0f * 2.0f - 1.0f;
  float py = (row + 0.5f) / 256.0f * 2.0f - 1.0f;

  ull pk = packed[t];
  uint f = (uint)pk;
  float gx = 0.0f, gy = 0.0f;
  if (f != 0xFFFFFFFFu) {
    const float4* fq = fh4 + ((size_t)b * F + f) * 4;
    float4 q1 = fq[1];
    float4 q2 = fq[2];
    float dpx = px - q1.x;
    float dpy = py - q1.y;
    float w1 = (dpx * q2.y - q2.x * dpy) * q2.z;   // bit-identical to k_raster
    float w2 = (q1.z * dpy - dpx * q1.w) * q2.z;
    float w0 = (1.0f - w1) - w2;
    const float4* aq = fa4 + ((size_t)b * F + f) * 2;
    float4 a0 = aq[0];
    float4 a1 = aq[1];
    gx = (w0 * a0.x + w1 * a0.z) + w2 * a1.x;
    gy = (w0 * a0.y + w1 * a0.w) + w2 * a1.y;
  }

  // grid_sample (align_corners=False, zero pad), exact ref op order
  float x = (gx + 1.0f) * 0.5f * 256.0f - 0.5f;
  float y = (gy + 1.0f) * 0.5f * 256.0f - 0.5f;
  float x0f = floorf(x), y0f = floorf(y);
  float wx1 = x - x0f, wx0 = 1.0f - wx1;
  float wy1 = y - y0f, wy0 = 1.0f - wy1;

  for (int ch = 0; ch < 3; ++ch) {
    int base = (b * 3 + ch) * 65536;
    float f00 = fetchpix(img, base, x0f, y0f);
    float f10 = fetchpix(img, base, x0f + 1.0f, y0f);
    float f01 = fetchpix(img, base, x0f, y0f + 1.0f);
    float f11 = fetchpix(img, base, x0f + 1.0f, y0f + 1.0f);
    float A  = wy0 * ((wx0 * f00) + (wx1 * f10));
    float Bv = wy1 * ((wx0 * f01) + (wx1 * f11));
    out[base + pix] = A + Bv;
  }
}

extern "C" void kernel_launch(void* const* d_in, const int* in_sizes, int n_in,
                              void* d_out, int out_size, void* d_ws, size_t ws_size,
                              hipStream_t stream) {
  const float* cam  = (const float*)d_in[0];
  const float* hv   = (const float*)d_in[1];
  const float* img  = (const float*)d_in[2];
  const float* camn = (const float*)d_in[3];
  const int* faces  = (const int*)d_in[4];

  const int B = in_sizes[0] / 3;            // 2
  const int N = in_sizes[1] / (3 * B);      // 5120
  const int F = in_sizes[4] / 3;            // 10240
  const int NCH64 = (F + 63) / 64;          // 160
  const int P = 65536;

  char* wsb = (char*)d_ws;
  size_t ofs = 0;
  float4* fh4   = (float4*)(wsb + ofs); ofs += (size_t)B * F * 4 * sizeof(float4);
  float4* fa4   = (float4*)(wsb + ofs); ofs += (size_t)B * F * 2 * sizeof(float4);
  float4* s3    = (float4*)(wsb + ofs); ofs += (size_t)B * F * 3 * sizeof(float4);
  float4* bboxs = (float4*)(wsb + ofs); ofs += (size_t)B * F * sizeof(float4);
  uint* bkt = (uint*)(wsb + ofs); ofs += (size_t)B * F * 4;
  uint* cnt = (uint*)(wsb + ofs); ofs += (size_t)B * K_BUCKETS * 4;
  uint* off = (uint*)(wsb + ofs); ofs += (size_t)B * K_BUCKETS * 4;
  float* lbC = (float*)(wsb + ofs); ofs += (size_t)B * NCH64 * 4;
  ofs = (ofs + 255) & ~(size_t)255;
  ull* packed = (ull*)(wsb + ofs); ofs += (size_t)B * P * sizeof(ull);

  int np = B * P;
  hipMemsetAsync(cnt, 0, (size_t)B * K_BUCKETS * 4, stream);
  int nf = B * F;
  k_faces<<<(nf + 255) / 256, 256, 0, stream>>>(faces, hv, cam, camn,
                                                fh4, fa4, bkt, cnt,
                                                packed, np, F, N, B);
  k_prefix<<<B, 1024, 0, stream>>>(cnt, off);
  k_scatter<<<(nf + 255) / 256, 256, 0, stream>>>(fh4, bkt, off, s3, bboxs,
                                                  lbC, F, NCH64, B);
  const int cps = (NCH64 + NSEG - 1) / NSEG;          // 3
  const int segUsed = (NCH64 + cps - 1) / cps;        // 54 non-empty segments
  int nwaves = segUsed * B * 1024;
  k_raster<<<nwaves / 2, 128, 0, stream>>>(s3, bboxs, lbC, packed, F, NCH64, B);
  k_sample<<<(np + 255) / 256, 256, 0, stream>>>(fh4, fa4, packed, img, (float*)d_out, F);
}

// Round 24
// 86.419 us; speedup vs baseline: 1.4182x; 1.0486x over previous
//
#include <hip/hip_runtime.h>
#include <stdint.h>

typedef unsigned int uint;
typedef unsigned long long ull;

// B=2, N=5120, F=10240, H=W=256. Bit-exact fp32 replication of the reference
// (contract off, IEEE div). Pipeline:
//   memset(cnt=0) -> k_faces (transform fused, per-face records, zmin bucket
//   counts, packed-init folded) -> k_prefix -> k_scatter (z-sorted records +
//   bbox + per-64-chunk lb array) ->
//   k_raster: WAVE-AUTONOMOUS. One wave = one 8x8-px tile x z-segment
//     (54*B*1024 waves, cps=3, 1 px/lane, no LDS, no barriers). Per 64-face
//     chunk: lane i culls face (prefetched bbox + SAT), ballot; iterate set
//     bits: readlane-broadcast 11 face scalars, branchless test, best =
//     packed u64 (z_bits<<32 | orig_f). Poll packed + publish best once per
//     GROUP chunks; wave exits when __all(lb >= known + TOL)  [NaN-safe].
//   -> k_sample recomputes winner barycentrics bit-identically + bilinear.
// FINAL (R24 = R20, best verified 86.6us). Refuted by counters: NSEG 160
// (loses local-best accumulation), GROUP 2/per-chunk checks (control
// overhead), 2px/lane (tail coupling), LDS staging (latency), acq_rel
// countdown & grid.sync (device-scope sync ~15-2000us on non-coherent XCD
// L2s), per-chunk polling (atomic bandwidth).
// Winner = lexicographic (z, orig_f) min == reference chunked argmin.
// Sorted record s3 = 3 float4/face: {v0x,v0y,e1x,e1y} {e2x,e2y,inv,z0}
//                                   {z1,z2,bits(orig_f),lb}; bbox separate.

#define K_BUCKETS 4096
#define ZLO 0.0f
#define ZHI 20.0f
#define TOL 2.5e-4f      // >=50x the ~5e-6 fp slack (z is a convex comb.)
#define NSEG 64          // z-segmentation granularity (cps = ceil(160/64) = 3)
#define PAD 0.004f       // conservative cull pad (>=100x fp slack)
#define GROUP 4          // chunks (of 64 faces) between poll/publish

__device__ __forceinline__ float clip11(float t) {
  return fminf(1.0f, fmaxf(-1.0f, t));
}

__device__ __forceinline__ float RL(float v, int j) {
  return __uint_as_float((uint)__builtin_amdgcn_readlane((int)__float_as_uint(v), j));
}

__global__ void k_faces(const int* __restrict__ faces,
                        const float* __restrict__ hv,
                        const float* __restrict__ cam,
                        const float* __restrict__ camn,
                        float4* __restrict__ fh4,   // B*F*4 (orig order)
                        float4* __restrict__ fa4,   // B*F*2 (orig order)
                        uint* __restrict__ bkt,     // B*F
                        uint* __restrict__ cnt,     // B*K
                        ull* __restrict__ packed, int np,
                        int F, int N, int B) {
#pragma clang fp contract(off)
  int t = blockIdx.x * 256 + threadIdx.x;
  int nthr = gridDim.x * 256;
  // fold packed-init here (stream order makes it visible to k_raster)
  for (int i = t; i < np; i += nthr) packed[i] = 0xFFFFFFFFFFFFFFFFull;
  if (t >= B * F) return;
  int b = t / F;
  int f = t - b * F;
  int i0 = faces[f * 3 + 0];
  int i1 = faces[f * 3 + 1];
  int i2 = faces[f * 3 + 2];
  float c0n = camn[b * 3 + 0], c1n = camn[b * 3 + 1], c2n = camn[b * 3 + 2];
  float c0o = cam[b * 3 + 0], c1o = cam[b * 3 + 1], c2o = cam[b * 3 + 2];

  float x0, y0, z0, x1, y1, z1, x2, y2, z2;
  float u0, v0, u1, v1, u2, v2;
#define XFORM(idx, X, Y, Z, U, V)                          \
  {                                                        \
    const float* p = hv + (size_t)(b * N + (idx)) * 3;     \
    float X0 = p[0], X1 = p[1], X2 = p[2];                 \
    float t0 = c0n * (X0 + c1n);                           \
    float t1 = c0n * (X1 + c2n);                           \
    float t2 = c0n * X2;                                   \
    X = clip11(t0);                                        \
    Y = clip11(-t1);                                       \
    Z = -t2 + 10.0f;                                       \
    float s0 = c0o * (X0 + c1o);                           \
    float s1 = c0o * (X1 + c2o);                           \
    U = clip11(s0);                                        \
    V = clip11(-s1);                                       \
  }
  XFORM(i0, x0, y0, z0, u0, v0)
  XFORM(i1, x1, y1, z1, u1, v1)
  XFORM(i2, x2, y2, z2, u2, v2)
#undef XFORM

  float e1x = x1 - x0;
  float e1y = y1 - y0;
  float e2x = x2 - x0;
  float e2y = y2 - y0;
  float d = (e1x * e2y) - (e2x * e1y);
  float inv;
  if (fabsf(d) > 1e-8f) {
    inv = 1.0f / d;                     // IEEE division
  } else {
    inv = __int_as_float(0x7fc00000);   // NaN -> inside test fails
  }
  float4* fq = fh4 + (size_t)t * 4;
  fq[0] = make_float4(fminf(x0, fminf(x1, x2)), fmaxf(x0, fmaxf(x1, x2)),
                      fminf(y0, fminf(y1, y2)), fmaxf(y0, fmaxf(y1, y2)));
  fq[1] = make_float4(x0, y0, e1x, e1y);
  fq[2] = make_float4(e2x, e2y, inv, z0);
  fq[3] = make_float4(z1, z2, 0.0f, 0.0f);

  float zmn = fminf(z0, fminf(z1, z2));
  int kb = (int)((zmn - ZLO) * ((float)K_BUCKETS / (ZHI - ZLO)));
  kb = min(max(kb, 0), K_BUCKETS - 1);
  bkt[t] = (uint)kb;
  atomicAdd(&cnt[b * K_BUCKETS + kb], 1u);

  float4* aq = fa4 + (size_t)t * 2;
  aq[0] = make_float4(u0, v0, u1, v1);
  aq[1] = make_float4(u2, v2, 0.0f, 0.0f);
}

// one block per batch; exclusive prefix over K_BUCKETS counts
__global__ void __launch_bounds__(1024) k_prefix(const uint* __restrict__ cnt,
                                                 uint* __restrict__ off) {
  __shared__ uint s[1024];
  int b = blockIdx.x;
  const uint* c = cnt + (size_t)b * K_BUCKETS;
  uint* o = off + (size_t)b * K_BUCKETS;
  int tid = threadIdx.x;
  uint v0 = c[tid * 4 + 0], v1 = c[tid * 4 + 1], v2 = c[tid * 4 + 2], v3 = c[tid * 4 + 3];
  uint sum = v0 + v1 + v2 + v3;
  s[tid] = sum;
  __syncthreads();
  for (int d = 1; d < 1024; d <<= 1) {
    uint t = (tid >= d) ? s[tid - d] : 0u;
    __syncthreads();
    s[tid] += t;
    __syncthreads();
  }
  uint run = s[tid] - sum;   // exclusive
  o[tid * 4 + 0] = run; run += v0;
  o[tid * 4 + 1] = run; run += v1;
  o[tid * 4 + 2] = run; run += v2;
  o[tid * 4 + 3] = run;
}

__global__ void k_scatter(const float4* __restrict__ fh4,
                          const uint* __restrict__ bkt,
                          uint* __restrict__ off,       // consumed as cursor
                          float4* __restrict__ s3,      // B*F*3 sorted records
                          float4* __restrict__ bboxs,   // B*F sorted bboxes
                          float* __restrict__ lbC,      // B*NCH64 chunk lbs
                          int F, int NCH64, int B) {
  int t = blockIdx.x * 256 + threadIdx.x;
  if (t >= B * F) return;
  int b = t / F;
  int f = t - b * F;
  uint kb = bkt[t];
  uint pos = atomicAdd(&off[b * K_BUCKETS + kb], 1u);
  const float4* s = fh4 + (size_t)t * 4;
  float4 q0 = s[0], q1 = s[1], q2 = s[2], q3 = s[3];
  q3.z = __uint_as_float((uint)f);
  q3.w = (kb == 0u) ? -1e30f : (ZLO + (float)kb * ((ZHI - ZLO) / (float)K_BUCKETS));
  float4* d = s3 + ((size_t)b * F + pos) * 3;
  d[0] = q1; d[1] = q2; d[2] = q3;
  bboxs[(size_t)b * F + pos] = q0;
  if ((pos & 63u) == 0u) lbC[b * NCH64 + (pos >> 6)] = q3.w;
}

// wave-autonomous raster: segUsed*B*1024 waves, 128-thr blocks (2 waves),
// one wave = 8x8-px tile (1 px/lane) x z-segment
__global__ void __launch_bounds__(128) k_raster(const float4* __restrict__ s3,
                                                const float4* __restrict__ bboxs,
                                                const float* __restrict__ lbC,
                                                ull* __restrict__ packed,
                                                int F, int NCH64, int B) {
#pragma clang fp contract(off)
  int w = blockIdx.x * 2 + (threadIdx.x >> 6);
  int lane = threadIdx.x & 63;
  int tilesPerSeg = B * 1024;
  int s = w / tilesPerSeg;              // segment-major: seg 0 launches first
  int rem = w - s * tilesPerSeg;
  int b = rem >> 10;
  int tile = rem & 1023;
  int tx = tile & 31, ty = tile >> 5;   // 32x32 tiles of 8x8 px
  int col = tx * 8 + (lane & 7);
  int row = ty * 8 + (lane >> 3);

  float px = (col + 0.5f) / 256.0f * 2.0f - 1.0f;
  float py = (row + 0.5f) / 256.0f * 2.0f - 1.0f;
  float txlo = (tx * 8 + 0.5f) / 256.0f * 2.0f - 1.0f - PAD;
  float txhi = (tx * 8 + 7.5f) / 256.0f * 2.0f - 1.0f + PAD;
  float tylo = (ty * 8 + 0.5f) / 256.0f * 2.0f - 1.0f - PAD;
  float tyhi = (ty * 8 + 7.5f) / 256.0f * 2.0f - 1.0f + PAD;

  const float4* __restrict__ s3B = s3 + (size_t)b * F * 3;
  const float4* __restrict__ bbB = bboxs + (size_t)b * F;
  const float* __restrict__ lbB = lbC + b * NCH64;
  size_t pix = ((size_t)b << 16) + (row << 8) + col;

  ull best = 0xFFFFFFFFFFFFFFFFull, pub = 0xFFFFFFFFFFFFFFFFull;

  int cps = (NCH64 + NSEG - 1) / NSEG;
  int ch0 = s * cps;
  int ch1 = min(NCH64, ch0 + cps);
  if (ch0 >= ch1) return;

  float4 bbCur = bbB[(size_t)(ch0 * 64 + lane)];   // prefetch first chunk

  for (int cg = ch0; cg < ch1; cg += GROUP) {
    // poll once per group: known = min(local best z, global z). Partial
    // publishes are mins over subsets -> valid upper bounds; NaN-safe:
    // no-candidate (NaN) makes the comparison false -> keep scanning.
    ull pk = __hip_atomic_load(packed + pix, __ATOMIC_RELAXED,
                               __HIP_MEMORY_SCOPE_AGENT);
    float kz = fminf(__uint_as_float((uint)(best >> 32)),
                     __uint_as_float((uint)(pk >> 32)));
    float lb = lbB[cg];   // lower-bounds zmin of all faces at index >= cg*64
    if (__all(lb >= kz + TOL)) break;

    int cend = min(cg + GROUP, ch1);
    for (int ch = cg; ch < cend; ++ch) {
      // issue next chunk's bbox load before this chunk's work (prefetch)
      int ni = (ch + 1 < ch1) ? ch + 1 : ch;
      float4 bbNxt = bbB[(size_t)(ni * 64 + lane)];

      int si = ch * 64 + lane;
      bool ok = (bbCur.x <= txhi && bbCur.y >= txlo &&
                 bbCur.z <= tyhi && bbCur.w >= tylo);
      float4 r1 = bbCur, r2 = bbCur, r3 = bbCur;   // defined defaults
      if (ok) {
        r1 = s3B[(size_t)si * 3 + 0];   // v0x v0y e1x e1y
        r2 = s3B[(size_t)si * 3 + 1];   // e2x e2y inv z0
        // SAT: separated if all padded-rect corners strictly outside one
        // triangle edge. NaN (degenerate) keeps face; inner test rejects it.
        float ax = r1.x, ay = r1.y;
        float e1x = r1.z, e1y = r1.w;
        float e2x = r2.x, e2y = r2.y;
        float sg = r2.z;
        float e3x = e2x - e1x, e3y = e2y - e1y;
        float bxx = ax + e1x, bxy = ay + e1y;
        float nx = -sg * e1y, ny = sg * e1x;
        float dotA = nx * ((nx > 0.0f ? txhi : txlo) - ax) +
                     ny * ((ny > 0.0f ? tyhi : tylo) - ay);
        nx = sg * e2y; ny = -sg * e2x;
        float dotB = nx * ((nx > 0.0f ? txhi : txlo) - ax) +
                     ny * ((ny > 0.0f ? tyhi : tylo) - ay);
        nx = -sg * e3y; ny = sg * e3x;
        float dotC = nx * ((nx > 0.0f ? txhi : txlo) - bxx) +
                     ny * ((ny > 0.0f ? tyhi : tylo) - bxy);
        ok = !(dotA < 0.0f) && !(dotB < 0.0f) && !(dotC < 0.0f);
      }
      if (ok) r3 = s3B[(size_t)si * 3 + 2];   // z1 z2 fo lb

      ull m = __ballot(ok);
      while (m) {
        int j = (int)__builtin_ctzll(m);
        m &= m - 1;
        // register broadcast from lane j (readlane -> SGPR, no memory)
        float v0x = RL(r1.x, j), v0y = RL(r1.y, j);
        float e1x = RL(r1.z, j), e1y = RL(r1.w, j);
        float e2x = RL(r2.x, j), e2y = RL(r2.y, j);
        float inv = RL(r2.z, j), z0 = RL(r2.w, j);
        float z1 = RL(r3.x, j), z2 = RL(r3.y, j);
        uint fo = (uint)__builtin_amdgcn_readlane((int)__float_as_uint(r3.z), j);
        float dpx = px - v0x;
        float dpy = py - v0y;
        float w1 = (dpx * e2y - e2x * dpy) * inv;
        float w2 = (e1x * dpy - dpx * e1y) * inv;
        float w0 = (1.0f - w1) - w2;
        bool inside = (w0 >= 0.0f) && (w1 >= 0.0f) && (w2 >= 0.0f);
        float z = (w0 * z0 + w1 * z1) + w2 * z2;
        ull cand = ((ull)__float_as_uint(z) << 32) | (ull)fo;
        // z > 0 always => float bits monotone => u64 compare is lex (z, f)
        best = (inside && cand < best) ? cand : best;
      }
      bbCur = bbNxt;
    }
    // publish improvements once per group (throttles atomic traffic)
    if (best < pub) { atomicMin(packed + pix, best); pub = best; }
  }
  if (best < pub) atomicMin(packed + pix, best);
}

__device__ __forceinline__ float fetchpix(const float* __restrict__ img, int base,
                                          float ixf, float iyf) {
  bool valid = (ixf >= 0.0f) && (ixf < 256.0f) && (iyf >= 0.0f) && (iyf < 256.0f);
  int ix = (int)fminf(255.0f, fmaxf(0.0f, ixf));
  int iy = (int)fminf(255.0f, fmaxf(0.0f, iyf));
  float v = img[base + iy * 256 + ix];
  return valid ? v : 0.0f;
}

__global__ void __launch_bounds__(256) k_sample(const float4* __restrict__ fh4,
                                                const float4* __restrict__ fa4,
                                                const ull* __restrict__ packed,
                                                const float* __restrict__ img,
                                                float* __restrict__ out,
                                                int F) {
#pragma clang fp contract(off)
  int t = blockIdx.x * 256 + threadIdx.x;   // over B*65536
  int b = t >> 16;
  int pix = t & 65535;
  int row = pix >> 8;
  int col = pix & 255;
  float px = (col + 0.5f) / 256.0f * 2.0f - 1.0f;
  float py = (row + 0.5f) / 256.0f * 2.0f - 1.0f;

  ull pk = packed[t];
  uint f = (uint)pk;
  float gx = 0.0f, gy = 0.0f;
  if (f != 0xFFFFFFFFu) {
    const float4* fq = fh4 + ((size_t)b * F + f) * 4;
    float4 q1 = fq[1];
    float4 q2 = fq[2];
    float dpx = px - q1.x;
    float dpy = py - q1.y;
    float w1 = (dpx * q2.y - q2.x * dpy) * q2.z;   // bit-identical to k_raster
    float w2 = (q1.z * dpy - dpx * q1.w) * q2.z;
    float w0 = (1.0f - w1) - w2;
    const float4* aq = fa4 + ((size_t)b * F + f) * 2;
    float4 a0 = aq[0];
    float4 a1 = aq[1];
    gx = (w0 * a0.x + w1 * a0.z) + w2 * a1.x;
    gy = (w0 * a0.y + w1 * a0.w) + w2 * a1.y;
  }

  // grid_sample (align_corners=False, zero pad), exact ref op order
  float x = (gx + 1.0f) * 0.5f * 256.0f - 0.5f;
  float y = (gy + 1.0f) * 0.5f * 256.0f - 0.5f;
  float x0f = floorf(x), y0f = floorf(y);
  float wx1 = x - x0f, wx0 = 1.0f - wx1;
  float wy1 = y - y0f, wy0 = 1.0f - wy1;

  for (int ch = 0; ch < 3; ++ch) {
    int base = (b * 3 + ch) * 65536;
    float f00 = fetchpix(img, base, x0f, y0f);
    float f10 = fetchpix(img, base, x0f + 1.0f, y0f);
    float f01 = fetchpix(img, base, x0f, y0f + 1.0f);
    float f11 = fetchpix(img, base, x0f + 1.0f, y0f + 1.0f);
    float A  = wy0 * ((wx0 * f00) + (wx1 * f10));
    float Bv = wy1 * ((wx0 * f01) + (wx1 * f11));
    out[base + pix] = A + Bv;
  }
}

extern "C" void kernel_launch(void* const* d_in, const int* in_sizes, int n_in,
                              void* d_out, int out_size, void* d_ws, size_t ws_size,
                              hipStream_t stream) {
  const float* cam  = (const float*)d_in[0];
  const float* hv   = (const float*)d_in[1];
  const float* img  = (const float*)d_in[2];
  const float* camn = (const float*)d_in[3];
  const int* faces  = (const int*)d_in[4];

  const int B = in_sizes[0] / 3;            // 2
  const int N = in_sizes[1] / (3 * B);      // 5120
  const int F = in_sizes[4] / 3;            // 10240
  const int NCH64 = (F + 63) / 64;          // 160
  const int P = 65536;

  char* wsb = (char*)d_ws;
  size_t ofs = 0;
  float4* fh4   = (float4*)(wsb + ofs); ofs += (size_t)B * F * 4 * sizeof(float4);
  float4* fa4   = (float4*)(wsb + ofs); ofs += (size_t)B * F * 2 * sizeof(float4);
  float4* s3    = (float4*)(wsb + ofs); ofs += (size_t)B * F * 3 * sizeof(float4);
  float4* bboxs = (float4*)(wsb + ofs); ofs += (size_t)B * F * sizeof(float4);
  uint* bkt = (uint*)(wsb + ofs); ofs += (size_t)B * F * 4;
  uint* cnt = (uint*)(wsb + ofs); ofs += (size_t)B * K_BUCKETS * 4;
  uint* off = (uint*)(wsb + ofs); ofs += (size_t)B * K_BUCKETS * 4;
  float* lbC = (float*)(wsb + ofs); ofs += (size_t)B * NCH64 * 4;
  ofs = (ofs + 255) & ~(size_t)255;
  ull* packed = (ull*)(wsb + ofs); ofs += (size_t)B * P * sizeof(ull);

  int np = B * P;
  hipMemsetAsync(cnt, 0, (size_t)B * K_BUCKETS * 4, stream);
  int nf = B * F;
  k_faces<<<(nf + 255) / 256, 256, 0, stream>>>(faces, hv, cam, camn,
                                                fh4, fa4, bkt, cnt,
                                                packed, np, F, N, B);
  k_prefix<<<B, 1024, 0, stream>>>(cnt, off);
  k_scatter<<<(nf + 255) / 256, 256, 0, stream>>>(fh4, bkt, off, s3, bboxs,
                                                  lbC, F, NCH64, B);
  const int cps = (NCH64 + NSEG - 1) / NSEG;          // 3
  const int segUsed = (NCH64 + cps - 1) / cps;        // 54 non-empty segments
  int nwaves = segUsed * B * 1024;
  k_raster<<<nwaves / 2, 128, 0, stream>>>(s3, bboxs, lbC, packed, F, NCH64, B);
  k_sample<<<(np + 255) / 256, 256, 0, stream>>>(fh4, fa4, packed, img, (float*)d_out, F);
}